// Round 15
// baseline (514.887 us; speedup 1.0000x reference)
//
#include <hip/hip_runtime.h>
#include <hip/hip_bf16.h>
#include <stdint.h>

typedef __bf16 bf16;
typedef __bf16 bf16x2_t __attribute__((ext_vector_type(2)));
typedef __bf16 bf16x4_t __attribute__((ext_vector_type(4)));
typedef __bf16 bf16x8_t __attribute__((ext_vector_type(8)));
typedef float f32x4_t __attribute__((ext_vector_type(4)));

#define DEVI __device__ __forceinline__

static constexpr int S = 2048;
static constexpr int D = 4096;
static constexpr int HD = 128;
static constexpr int KVW = 1024;   // 8 kv-heads * 128
static constexpr int NQKV = 6144;  // 4096 Q + 1024 K + 1024 V

__device__ const float NF4LUT[16] = {
  -1.0f, -0.6961928009986877f, -0.5250730514526367f, -0.39491748809814453f,
  -0.28444138169288635f, -0.18477343022823334f, -0.09105003625154495f, 0.0f,
  0.07958029955625534f, 0.16093020141124725f, 0.24611230194568634f,
  0.33791524171829224f, 0.44070982933044434f, 0.5626170039176941f,
  0.7229568362236023f, 1.0f };

DEVI void gld_lds16(const bf16* g, bf16* l) {
  __builtin_amdgcn_global_load_lds((__attribute__((address_space(1))) void*)g,
                                   (__attribute__((address_space(3))) void*)l,
                                   16, 0, 0);
}

// swizzle for [row][64]-element bf16 LDS tiles (128B rows): element XOR
// (row&7)<<3 -> byte XOR (row&7)*16 -> bank groups 4*(q^(r&7)) cover all 32 banks
DEVI int swz64(int row) { return (row & 7) << 3; }

// ---------------- prep: x fp32->bf16 convert + lora-B packing, one launch ----

__global__ __launch_bounds__(256) void k_prep(
    const float* __restrict__ x, bf16* __restrict__ xbf,
    const float* __restrict__ qB, const float* __restrict__ kB,
    const float* __restrict__ vB, const float* __restrict__ oB,
    bf16* __restrict__ Bqkv, bf16* __restrict__ Bo) {
  int b = blockIdx.x;
  if (b < 8192) {
    int i = (b * 256 + threadIdx.x) * 4;
    float4 v = *(const float4*)(x + i);
    bf16x4_t o;
    o[0] = (bf16)v.x; o[1] = (bf16)v.y; o[2] = (bf16)v.z; o[3] = (bf16)v.w;
    *(bf16x4_t*)(xbf + i) = o;
  } else {
    int r = (b - 8192) * 256 + threadIdx.x;
    if (r >= 10240) return;
    bf16* dst; const float* src; int off;
    if (r < 4096)      { dst = Bqkv + (size_t)r * 64;        src = qB + (size_t)r * 16;          off = 0; }
    else if (r < 5120) { dst = Bqkv + (size_t)r * 64;        src = kB + (size_t)(r - 4096) * 16; off = 16; }
    else if (r < 6144) { dst = Bqkv + (size_t)r * 64;        src = vB + (size_t)(r - 5120) * 16; off = 32; }
    else               { dst = Bo + (size_t)(r - 6144) * 64; src = oB + (size_t)(r - 6144) * 16; off = 0; }
    bf16 row[64];
#pragma unroll
    for (int i = 0; i < 64; ++i) row[i] = (bf16)0.f;
#pragma unroll
    for (int i = 0; i < 16; ++i) row[off + i] = (bf16)src[i];
#pragma unroll
    for (int i = 0; i < 8; ++i)
      *(bf16x8_t*)(dst + i * 8) = *(bf16x8_t*)(row + i * 8);
  }
}

DEVI void dequant8(const int* idx, float sc, bf16* out) {
  int4 a = *(const int4*)idx;
  int4 b = *(const int4*)(idx + 4);
  bf16x8_t o;
  o[0] = (bf16)(NF4LUT[a.x] * sc);
  o[1] = (bf16)(NF4LUT[a.y] * sc);
  o[2] = (bf16)(NF4LUT[a.z] * sc);
  o[3] = (bf16)(NF4LUT[a.w] * sc);
  o[4] = (bf16)(NF4LUT[b.x] * sc);
  o[5] = (bf16)(NF4LUT[b.y] * sc);
  o[6] = (bf16)(NF4LUT[b.z] * sc);
  o[7] = (bf16)(NF4LUT[b.w] * sc);
  *(bf16x8_t*)out = o;
}

__global__ __launch_bounds__(256) void k_dequant(const int* __restrict__ idx,
                                                 const float* __restrict__ am,
                                                 bf16* __restrict__ out, int n) {
  int base = (blockIdx.x * 256 + threadIdx.x) * 8;
  if (base >= n) return;
  dequant8(idx + base, am[base >> 6], out + base);
}

// merged Q/K/V dequant into contiguous Wbuf (regions block-aligned)
__global__ __launch_bounds__(256) void k_dequant3(
    const int* __restrict__ i0, const float* __restrict__ a0,
    const int* __restrict__ i1, const float* __restrict__ a1,
    const int* __restrict__ i2, const float* __restrict__ a2,
    bf16* __restrict__ out) {
  size_t base = ((size_t)blockIdx.x * 256 + threadIdx.x) * 8;
  const int* idx; const float* am; size_t off;
  if (base < (size_t)4096 * 4096)      { idx = i0; am = a0; off = base; }
  else if (base < (size_t)5120 * 4096) { idx = i1; am = a1; off = base - (size_t)4096 * 4096; }
  else                                 { idx = i2; am = a2; off = base - (size_t)5120 * 4096; }
  dequant8(idx + off, am[off >> 6], out + base);
}

// merged RoPE for Q (width 4096, pre-scaled by 1/sqrt(128)*log2e for exp2
// softmax) and K (width 1024) sections of qkv[.][6144]
__global__ __launch_bounds__(256) void k_rope2(const bf16* __restrict__ qkv,
                                               bf16* __restrict__ qbf,
                                               bf16* __restrict__ kbf,
                                               const float* __restrict__ cs,
                                               const float* __restrict__ sn) {
  const float QSCL = 0.08838834764831843f * 1.4426950408889634f;
  int p = blockIdx.x * 256 + threadIdx.x;
  const bf16* in; bf16* out; int s, q; float scl;
  if (p < S * 2048) {
    s = p >> 11; q = p & 2047;
    int k = q & 63, col = ((q >> 6) << 7) + (k << 1);
    in = qkv + (size_t)s * NQKV + col;
    out = qbf + (size_t)s * D + col;
    scl = QSCL;
  } else {
    int p2 = p - S * 2048;
    s = p2 >> 9; q = p2 & 511;
    int k = q & 63, col = ((q >> 6) << 7) + (k << 1);
    in = qkv + (size_t)s * NQKV + 4096 + col;
    out = kbf + (size_t)s * KVW + col;
    scl = 1.0f;
  }
  int k = q & 63;
  bf16x2_t v = *(const bf16x2_t*)in;
  float xr = (float)v[0], xi = (float)v[1];
  float c = cs[s * 64 + k], si = sn[s * 64 + k];
  bf16x2_t o;
  o[0] = (bf16)((xr * c - xi * si) * scl);
  o[1] = (bf16)((xr * si + xi * c) * scl);
  *(bf16x2_t*)out = o;
}

// transpose V section of qkv (cols 5120..6143) into vT[1024][2048]
__global__ __launch_bounds__(256) void k_transpose_v(const bf16* __restrict__ qkv,
                                                     bf16* __restrict__ vT) {
  __shared__ bf16 tl[64][72];
  const int t = threadIdx.x;
  const int s0 = blockIdx.x * 64, d0 = blockIdx.y * 64;
  int r = t >> 3, c = (t & 7) * 8;
  *(bf16x8_t*)&tl[r][c] = *(const bf16x8_t*)&qkv[(size_t)(s0 + r) * NQKV + 5120 + d0 + c];
  *(bf16x8_t*)&tl[r + 32][c] = *(const bf16x8_t*)&qkv[(size_t)(s0 + r + 32) * NQKV + 5120 + d0 + c];
  __syncthreads();
  int dr = t >> 3, sc = (t & 7) * 8;
  bf16x8_t o0, o1;
#pragma unroll
  for (int i = 0; i < 8; ++i) { o0[i] = tl[sc + i][dr]; o1[i] = tl[sc + i][dr + 32]; }
  *(bf16x8_t*)&vT[(size_t)(d0 + dr) * S + s0 + sc] = o0;
  *(bf16x8_t*)&vT[(size_t)(d0 + dr + 32) * S + s0 + sc] = o1;
}

// ---------------- skinny LoRA-left GEMM, split-K=16: part[ks][s][r]
__global__ __launch_bounds__(256) void k_lora_skinny(
    const bf16* __restrict__ X, const float* __restrict__ A0,
    const float* __restrict__ A1, const float* __restrict__ A2,
    float* __restrict__ part) {
  __shared__ __align__(16) bf16 Xs[128 * 32];
  __shared__ __align__(16) bf16 Bs[64 * 32];
  const int tid = threadIdx.x;
  const int rowBase = blockIdx.x * 128;
  const int k0base = blockIdx.y * 256;
  const int l = tid & 63, wv = tid >> 6;
  const int wr = (wv >> 1) * 64, wc = (wv & 1) * 32;
  const int lr = l & 15, lk = (l >> 4) * 8, lg = (l >> 4) * 4;

  f32x4_t acc[4][2];
#pragma unroll
  for (int m = 0; m < 4; ++m)
#pragma unroll
    for (int n = 0; n < 2; ++n) acc[m][n] = f32x4_t{0.f, 0.f, 0.f, 0.f};

  for (int k0 = k0base; k0 < k0base + 256; k0 += 32) {
    __syncthreads();
    gld_lds16(X + (size_t)(rowBase + (tid >> 2)) * D + k0 + (tid & 3) * 8, Xs + tid * 8);
    gld_lds16(X + (size_t)(rowBase + 64 + (tid >> 2)) * D + k0 + (tid & 3) * 8,
              Xs + 2048 + tid * 8);
#pragma unroll
    for (int j = 0; j < 2; ++j) {
      int r = j * 32 + (tid >> 3);
      int c = (tid & 7) * 4;
      const float* Ap = nullptr; int rr = r;
      if (r < 16) Ap = A0;
      else if (r < 32) { Ap = A1; rr = r - 16; }
      else if (r < 48) { Ap = A2; rr = r - 32; }
      bf16x4_t b = {bf16(0.f), bf16(0.f), bf16(0.f), bf16(0.f)};
      if (Ap) {
        float4 v = *(const float4*)&Ap[(size_t)rr * D + k0 + c];
        b[0] = (bf16)v.x; b[1] = (bf16)v.y; b[2] = (bf16)v.z; b[3] = (bf16)v.w;
      }
      *(bf16x4_t*)&Bs[r * 32 + c] = b;
    }
    __syncthreads();
    bf16x8_t af[4], bfr[2];
#pragma unroll
    for (int m = 0; m < 4; ++m)
      af[m] = *(const bf16x8_t*)&Xs[(wr + m * 16 + lr) * 32 + lk];
#pragma unroll
    for (int n = 0; n < 2; ++n)
      bfr[n] = *(const bf16x8_t*)&Bs[(wc + n * 16 + lr) * 32 + lk];
#pragma unroll
    for (int m = 0; m < 4; ++m)
#pragma unroll
      for (int n = 0; n < 2; ++n)
        acc[m][n] = __builtin_amdgcn_mfma_f32_16x16x32_bf16(af[m], bfr[n],
                                                            acc[m][n], 0, 0, 0);
  }
#pragma unroll
  for (int m = 0; m < 4; ++m)
#pragma unroll
    for (int n = 0; n < 2; ++n)
#pragma unroll
      for (int g = 0; g < 4; ++g)
        part[(size_t)blockIdx.y * (2048 * 64) +
             (size_t)(rowBase + wr + m * 16 + lg + g) * 64 + wc + n * 16 + lr] =
            acc[m][n][g];
}

__global__ __launch_bounds__(256) void k_lora_reduce(const float* __restrict__ part,
                                                     bf16* __restrict__ out) {
  int i = blockIdx.x * 256 + threadIdx.x;
  float s = 0.f;
#pragma unroll
  for (int j = 0; j < 16; ++j) s += part[j * 131072 + i];
  out[i] = (bf16)(2.0f * s);
}

// ---------------- main GEMM: out[s][n] = sum_d A[s][d]*W[n][d] + rank-64 tail
// 128x128 tile, BK=64 (XOR-swizzled LDS), 4 waves, 16x16x32 bf16 MFMA.
// Column-major block order within XCD-contiguous chunks for W-panel L2 reuse.
// (r7/r9/r13-proven: ~1030 TF, 0 bank conflicts. r8 dbuf and r10 fused-epilogue
//  variants both regressed via occupancy/L2-reuse loss — keep this lean.)

template <int OUT_BF16>
__global__ __launch_bounds__(256) void k_gemm_lora(
    const bf16* __restrict__ Ag, const bf16* __restrict__ Wg,
    const bf16* __restrict__ xA64, const bf16* __restrict__ Bl64,
    void* __restrict__ outp, int N, int K) {
  __shared__ __align__(16) bf16 As[128 * 64];
  __shared__ __align__(16) bf16 Bs[128 * 64];
  const int tid = threadIdx.x;
  const int gy = gridDim.y;                 // 16 row-blocks
  const int nwg = gridDim.x * gy;
  const int flat = blockIdx.y * gridDim.x + blockIdx.x;
  const int cpx = nwg >> 3;
  const int bid = (flat & 7) * cpx + (flat >> 3);   // XCD-contiguous chunks
  const int colBase = (bid / gy) * 128;             // column-major within chunk
  const int rowBase = (bid % gy) * 128;
  const int l = tid & 63, wv = tid >> 6;
  const int wr = (wv >> 1) * 64, wc = (wv & 1) * 64;
  const int lr = l & 15, lk = (l >> 4) * 8;

  f32x4_t acc[4][4];
#pragma unroll
  for (int m = 0; m < 4; ++m)
#pragma unroll
    for (int n = 0; n < 4; ++n) acc[m][n] = f32x4_t{0.f, 0.f, 0.f, 0.f};

  // stage a [128][64] tile (rows at stride ld from src), source-swizzled
  auto stage = [&](const bf16* src, size_t ld, bf16* dst) {
#pragma unroll
    for (int j = 0; j < 4; ++j) {
      int r = j * 32 + (tid >> 3);
      int c = ((tid & 7) * 8) ^ swz64(r);
      gld_lds16(src + (size_t)r * ld + c, dst + j * 2048 + tid * 8);
    }
  };

  auto compute = [&]() {
#pragma unroll
    for (int kk = 0; kk < 2; ++kk) {
      bf16x8_t af[4], bfr[4];
#pragma unroll
      for (int m = 0; m < 4; ++m) {
        int r = wr + m * 16 + lr;
        af[m] = *(const bf16x8_t*)&As[r * 64 + ((kk * 32 + lk) ^ swz64(r))];
      }
#pragma unroll
      for (int n = 0; n < 4; ++n) {
        int r = wc + n * 16 + lr;
        bfr[n] = *(const bf16x8_t*)&Bs[r * 64 + ((kk * 32 + lk) ^ swz64(r))];
      }
      __builtin_amdgcn_s_setprio(1);
#pragma unroll
      for (int m = 0; m < 4; ++m)
#pragma unroll
        for (int n = 0; n < 4; ++n)
          acc[m][n] = __builtin_amdgcn_mfma_f32_16x16x32_bf16(af[m], bfr[n],
                                                              acc[m][n], 0, 0, 0);
      __builtin_amdgcn_s_setprio(0);
    }
  };

  for (int k0 = 0; k0 < K; k0 += 64) {
    __syncthreads();
    stage(Ag + (size_t)rowBase * K + k0, K, As);
    stage(Wg + (size_t)colBase * K + k0, K, Bs);
    __syncthreads();
    compute();
  }

  // rank-64 LoRA tail: one BK=64 step from xA64 [M][64] and Bl64 [N][64]
  __syncthreads();
  stage(xA64 + (size_t)rowBase * 64, 64, As);
  stage(Bl64 + (size_t)colBase * 64, 64, Bs);
  __syncthreads();
  compute();

#pragma unroll
  for (int m = 0; m < 4; ++m)
#pragma unroll
    for (int n = 0; n < 4; ++n)
#pragma unroll
      for (int g = 0; g < 4; ++g) {
        int grow = rowBase + wr + m * 16 + ((l >> 4) << 2) + g;
        int gcol = colBase + wc + n * 16 + (l & 15);
        if (OUT_BF16)
          ((bf16*)outp)[(size_t)grow * N + gcol] = (bf16)acc[m][n][g];
        else
          ((float*)outp)[(size_t)grow * N + gcol] = acc[m][n][g];
      }
}

// ---------------- flash attention (causal, GQA 4:1) ----------------
// 512 thr / 8 waves = 4 row-groups x 2 kv-halves (split-KV specialization).
// Wave (rg,cg): 32 Q-rows, kv half cg of each 64-tile -> per-wave LDS traffic
// halved vs r14 (K 8KB + V 8KB per tile). Independent online softmax per
// half (mrun sentinel -30000 so fully-masked half-tiles give P=0); 2-way
// flash-decode merge at the end through Kt/Vt reused as f32 scratch.

__global__ __launch_bounds__(512, 4) void k_flash(const bf16* __restrict__ Qg,
                                                  const bf16* __restrict__ Kg,
                                                  const bf16* __restrict__ vTg,
                                                  bf16* __restrict__ Og) {
  __shared__ __align__(16) bf16 Kt[2][64 * 128];   // 32 KB
  __shared__ __align__(16) bf16 Vt[2][128 * 64];   // 32 KB
  __shared__ __align__(16) bf16 Pl[8][32 * 32];    // 16 KB
  const int tid = threadIdx.x, l = tid & 63, wv = tid >> 6;   // wv 0..7
  const int rg = wv & 3, cg = wv >> 2;
  const int h = blockIdx.y, hkv = h >> 2;
  const int qb = (h < 16) ? (15 - (int)blockIdx.x) : (int)blockIdx.x;
  const int lr = l & 15, lk = (l >> 4) * 8, lg = (l >> 4) * 4;
  const int swz = (lr & 7) << 3;

  const int R0 = qb * 128 + rg * 32;
  bf16x8_t qf[2][4];
#pragma unroll
  for (int m = 0; m < 2; ++m)
#pragma unroll
    for (int s4 = 0; s4 < 4; ++s4)
      qf[m][s4] = *(const bf16x8_t*)&Qg[(size_t)(R0 + m * 16 + lr) * D + h * HD +
                                        s4 * 32 + lk];

  f32x4_t O[2][8];
#pragma unroll
  for (int m = 0; m < 2; ++m)
#pragma unroll
    for (int of = 0; of < 8; ++of) O[m][of] = f32x4_t{0.f, 0.f, 0.f, 0.f};
  float mrun[2][4], lpart[2][4];
#pragma unroll
  for (int m = 0; m < 2; ++m)
#pragma unroll
    for (int g = 0; g < 4; ++g) { mrun[m][g] = -30000.f; lpart[m][g] = 0.f; }

  auto stage = [&](int b, int t) {
    const int kv0 = t * 64;
#pragma unroll
    for (int j = 0; j < 2; ++j) {
      int kr = j * 32 + (tid >> 4);                    // 0..63
      int kc = ((tid & 15) * 8) ^ ((kr & 7) << 3);
      gld_lds16(Kg + (size_t)(kv0 + kr) * KVW + hkv * HD + kc,
                &Kt[b][j * 4096 + tid * 8]);
    }
#pragma unroll
    for (int j = 0; j < 2; ++j) {
      int vr = j * 64 + (tid >> 3);                    // 0..127
      int vc = ((tid & 7) * 8) ^ ((vr & 7) << 3);
      gld_lds16(vTg + (size_t)(hkv * HD + vr) * S + kv0 + vc,
                &Vt[b][j * 4096 + tid * 8]);
    }
  };

  const int nt = 2 * qb + 2;
  stage(0, 0);

  for (int t = 0; t < nt; ++t) {
    __syncthreads();
    if (t + 1 < nt) stage((t + 1) & 1, t + 1);
    const bf16* Kb = Kt[t & 1];
    const bf16* Vb = Vt[t & 1];
    const int kvb = t * 64 + cg * 32;                  // this wave's kv half

    // S = Q K^T over this wave's 32-kv half (logits in log2 units)
    f32x4_t sc[2][2];
#pragma unroll
    for (int m = 0; m < 2; ++m)
#pragma unroll
      for (int cb = 0; cb < 2; ++cb) sc[m][cb] = f32x4_t{0.f, 0.f, 0.f, 0.f};
#pragma unroll
    for (int cb = 0; cb < 2; ++cb) {
      __builtin_amdgcn_s_setprio(1);
#pragma unroll
      for (int s4 = 0; s4 < 4; ++s4) {
        bf16x8_t kf = *(const bf16x8_t*)&Kb[(cg * 32 + cb * 16 + lr) * 128 +
                                            ((s4 * 32 + lk) ^ swz)];
#pragma unroll
        for (int m = 0; m < 2; ++m)
          sc[m][cb] = __builtin_amdgcn_mfma_f32_16x16x32_bf16(qf[m][s4], kf,
                                                              sc[m][cb], 0, 0, 0);
      }
      __builtin_amdgcn_s_setprio(0);
    }

    if (t >= 2 * qb) {
#pragma unroll
      for (int m = 0; m < 2; ++m)
#pragma unroll
        for (int cb = 0; cb < 2; ++cb)
#pragma unroll
          for (int g = 0; g < 4; ++g)
            if (kvb + cb * 16 + lr > R0 + m * 16 + lg + g) sc[m][cb][g] = -1e30f;
    }

    // local per-lane tile max; defer-max test (wave-uniform branch)
    float lmax[2][4];
    bool ok = true;
#pragma unroll
    for (int m = 0; m < 2; ++m)
#pragma unroll
      for (int g = 0; g < 4; ++g) {
        lmax[m][g] = fmaxf(sc[m][0][g], sc[m][1][g]);
        ok &= (lmax[m][g] <= mrun[m][g] + 8.0f);
      }
    if (!__all(ok)) {
#pragma unroll
      for (int m = 0; m < 2; ++m)
#pragma unroll
        for (int g = 0; g < 4; ++g) {
          float mx = lmax[m][g];
          mx = fmaxf(mx, __shfl_xor(mx, 1));
          mx = fmaxf(mx, __shfl_xor(mx, 2));
          mx = fmaxf(mx, __shfl_xor(mx, 4));
          mx = fmaxf(mx, __shfl_xor(mx, 8));
          float mnew = fmaxf(mrun[m][g], mx);
          float corr = exp2f(mrun[m][g] - mnew);
          mrun[m][g] = mnew;
          lpart[m][g] *= corr;
#pragma unroll
          for (int of = 0; of < 8; ++of) O[m][of][g] *= corr;
        }
    }

    // P = exp2(S - mrun); per-lane denominator; P -> wave-private swizzled LDS
#pragma unroll
    for (int m = 0; m < 2; ++m)
#pragma unroll
      for (int cb = 0; cb < 2; ++cb)
#pragma unroll
        for (int g = 0; g < 4; ++g) {
          float p = exp2f(sc[m][cb][g] - mrun[m][g]);
          lpart[m][g] += p;
          int row = m * 16 + lg + g;
          Pl[wv][row * 32 + ((cb * 16 + lr) ^ ((row & 3) << 3))] = (bf16)p;
        }

    // O += P V (this half's 32 kv)
    bf16x8_t pf[2];
#pragma unroll
    for (int m = 0; m < 2; ++m) {
      int row = m * 16 + lr;
      pf[m] = *(const bf16x8_t*)&Pl[wv][row * 32 + (lk ^ ((row & 3) << 3))];
    }
#pragma unroll
    for (int of = 0; of < 8; ++of) {
      bf16x8_t vf = *(const bf16x8_t*)&Vb[(of * 16 + lr) * 64 +
                                          ((cg * 32 + lk) ^ swz)];
      __builtin_amdgcn_s_setprio(1);
#pragma unroll
      for (int m = 0; m < 2; ++m)
        O[m][of] = __builtin_amdgcn_mfma_f32_16x16x32_bf16(pf[m], vf, O[m][of],
                                                           0, 0, 0);
      __builtin_amdgcn_s_setprio(0);
    }
  }

  // reduce per-lane denominators across the 16-lane groups
  float lsum[2][4];
#pragma unroll
  for (int m = 0; m < 2; ++m)
#pragma unroll
    for (int g = 0; g < 4; ++g) {
      float r = lpart[m][g];
      r += __shfl_xor(r, 1); r += __shfl_xor(r, 2);
      r += __shfl_xor(r, 4); r += __shfl_xor(r, 8);
      lsum[m][g] = r;
    }

  // 2-way split-KV merge: cg1 publishes (O, m, l) via Kt/Vt-as-f32 scratch
  __syncthreads();
  float* scr = (rg < 2) ? ((float*)Kt + rg * 4096) : ((float*)Vt + (rg - 2) * 4096);
  float* mscr = (float*)Pl;
  if (cg == 1) {
#pragma unroll
    for (int m = 0; m < 2; ++m)
#pragma unroll
      for (int of = 0; of < 8; ++of)
#pragma unroll
        for (int g = 0; g < 4; ++g)
          scr[(m * 16 + lg + g) * 128 + of * 16 + lr] = O[m][of][g];
    if (lr == 0) {
#pragma unroll
      for (int m = 0; m < 2; ++m)
#pragma unroll
        for (int g = 0; g < 4; ++g) {
          int row = m * 16 + lg + g;
          mscr[rg * 64 + row * 2] = mrun[m][g];
          mscr[rg * 64 + row * 2 + 1] = lsum[m][g];
        }
    }
  }
  __syncthreads();
  if (cg == 0) {
    float a1[2][4], a2[2][4], inv[2][4];
#pragma unroll
    for (int m = 0; m < 2; ++m)
#pragma unroll
      for (int g = 0; g < 4; ++g) {
        int row = m * 16 + lg + g;
        float m2 = mscr[rg * 64 + row * 2];
        float l2 = mscr[rg * 64 + row * 2 + 1];
        float mn = fmaxf(mrun[m][g], m2);
        a1[m][g] = exp2f(mrun[m][g] - mn);
        a2[m][g] = exp2f(m2 - mn);
        inv[m][g] = 1.0f / (lsum[m][g] * a1[m][g] + l2 * a2[m][g]);
      }
#pragma unroll
    for (int m = 0; m < 2; ++m)
#pragma unroll
      for (int of = 0; of < 8; ++of)
#pragma unroll
        for (int g = 0; g < 4; ++g) {
          int row = m * 16 + lg + g;
          float o2 = scr[row * 128 + of * 16 + lr];
          float o = (O[m][of][g] * a1[m][g] + o2 * a2[m][g]) * inv[m][g];
          Og[(size_t)(R0 + row) * D + h * HD + of * 16 + lr] = (bf16)o;
        }
  }
}

// ---------------- launch ----------------

extern "C" void kernel_launch(void* const* d_in, const int* in_sizes, int n_in,
                              void* d_out, int out_size, void* d_ws, size_t ws_size,
                              hipStream_t stream) {
  const float* x    = (const float*)d_in[0];
  const float* cosb = (const float*)d_in[1];
  const float* sinb = (const float*)d_in[2];
  const int*   wq_idx = (const int*)d_in[4];
  const float* wq_am  = (const float*)d_in[5];
  const float* wq_A   = (const float*)d_in[6];
  const float* wq_B   = (const float*)d_in[7];
  const int*   wk_idx = (const int*)d_in[8];
  const float* wk_am  = (const float*)d_in[9];
  const float* wk_A   = (const float*)d_in[10];
  const float* wk_B   = (const float*)d_in[11];
  const int*   wv_idx = (const int*)d_in[12];
  const float* wv_am  = (const float*)d_in[13];
  const float* wv_A   = (const float*)d_in[14];
  const float* wv_B   = (const float*)d_in[15];
  const int*   wo_idx = (const int*)d_in[16];
  const float* wo_am  = (const float*)d_in[17];
  const float* wo_A   = (const float*)d_in[18];
  const float* wo_B   = (const float*)d_in[19];

  char* w = (char*)d_ws;
  auto alloc = [&](size_t bytes) {
    char* p = w;
    w += (bytes + 255) & ~(size_t)255;
    return p;
  };
  bf16*  xbf   = (bf16*)alloc((size_t)S * D * 2);            // 16 MB
  bf16*  Wbuf  = (bf16*)alloc((size_t)NQKV * 4096 * 2);      // 50 MB
  bf16*  qkv   = (bf16*)alloc((size_t)S * NQKV * 2);         // 25 MB
  bf16*  qbf   = (bf16*)alloc((size_t)S * D * 2);            // 16 MB
  bf16*  kbf   = (bf16*)alloc((size_t)S * KVW * 2);          // 4 MB
  bf16*  vT    = (bf16*)alloc((size_t)KVW * S * 2);          // 4 MB
  bf16*  abf   = (bf16*)alloc((size_t)S * D * 2);            // 16 MB
  float* part  = (float*)alloc((size_t)16 * S * 64 * 4);     // 8 MB
  bf16*  xA64  = (bf16*)alloc((size_t)S * 64 * 2);
  bf16*  xA64o = (bf16*)alloc((size_t)S * 64 * 2);
  bf16*  Bqkv  = (bf16*)alloc((size_t)NQKV * 64 * 2);
  bf16*  Bo64  = (bf16*)alloc((size_t)4096 * 64 * 2);

  // prep (x convert + lora-B pack, one launch)
  k_prep<<<8232, 256, 0, stream>>>(x, xbf, wq_B, wk_B, wv_B, wo_B, Bqkv, Bo64);
  k_lora_skinny<<<dim3(16, 16), 256, 0, stream>>>(xbf, wq_A, wk_A, wv_A, part);
  k_lora_reduce<<<512, 256, 0, stream>>>(part, xA64);

  // merged QKV dequant + projection (N = 6144)
  k_dequant3<<<12288, 256, 0, stream>>>(wq_idx, wq_am, wk_idx, wk_am,
                                        wv_idx, wv_am, Wbuf);
  k_gemm_lora<1><<<dim3(48, 16), 256, 0, stream>>>(xbf, Wbuf, xA64, Bqkv,
                                                   qkv, NQKV, D);
  k_rope2<<<20480, 256, 0, stream>>>(qkv, qbf, kbf, cosb, sinb);
  k_transpose_v<<<dim3(32, 16), 256, 0, stream>>>(qkv, vT);

  // attention (512-thread blocks, 8 waves, split-KV)
  k_flash<<<dim3(16, 32), 512, 0, stream>>>(qbf, kbf, vT, abf);

  // output projection
  k_lora_skinny<<<dim3(16, 16), 256, 0, stream>>>(abf, wo_A, nullptr, nullptr, part);
  k_lora_reduce<<<512, 256, 0, stream>>>(part, xA64o);
  k_dequant<<<8192, 256, 0, stream>>>(wo_idx, wo_am, Wbuf, 4096 * 4096);
  k_gemm_lora<0><<<dim3(32, 16), 256, 0, stream>>>(abf, Wbuf, xA64o, Bo64,
                                                   (float*)d_out, D, D);
}

// Round 16
// 372.588 us; speedup vs baseline: 1.3819x; 1.3819x over previous
//
#include <hip/hip_runtime.h>
#include <hip/hip_bf16.h>
#include <stdint.h>

typedef __bf16 bf16;
typedef __bf16 bf16x2_t __attribute__((ext_vector_type(2)));
typedef __bf16 bf16x4_t __attribute__((ext_vector_type(4)));
typedef __bf16 bf16x8_t __attribute__((ext_vector_type(8)));
typedef float f32x4_t __attribute__((ext_vector_type(4)));

#define DEVI __device__ __forceinline__

static constexpr int S = 2048;
static constexpr int D = 4096;
static constexpr int HD = 128;
static constexpr int KVW = 1024;   // 8 kv-heads * 128
static constexpr int NQKV = 6144;  // 4096 Q + 1024 K + 1024 V

__device__ const float NF4LUT[16] = {
  -1.0f, -0.6961928009986877f, -0.5250730514526367f, -0.39491748809814453f,
  -0.28444138169288635f, -0.18477343022823334f, -0.09105003625154495f, 0.0f,
  0.07958029955625534f, 0.16093020141124725f, 0.24611230194568634f,
  0.33791524171829224f, 0.44070982933044434f, 0.5626170039176941f,
  0.7229568362236023f, 1.0f };

DEVI void gld_lds16(const bf16* g, bf16* l) {
  __builtin_amdgcn_global_load_lds((__attribute__((address_space(1))) void*)g,
                                   (__attribute__((address_space(3))) void*)l,
                                   16, 0, 0);
}

// swizzle for [row][64]-element bf16 LDS tiles (128B rows): element XOR
// (row&7)<<3 -> byte XOR (row&7)*16 -> bank groups 4*(q^(r&7)) cover all 32 banks
DEVI int swz64(int row) { return (row & 7) << 3; }

// ---------------- prep: x fp32->bf16 convert + lora-B packing, one launch ----

__global__ __launch_bounds__(256) void k_prep(
    const float* __restrict__ x, bf16* __restrict__ xbf,
    const float* __restrict__ qB, const float* __restrict__ kB,
    const float* __restrict__ vB, const float* __restrict__ oB,
    bf16* __restrict__ Bqkv, bf16* __restrict__ Bo) {
  int b = blockIdx.x;
  if (b < 8192) {
    int i = (b * 256 + threadIdx.x) * 4;
    float4 v = *(const float4*)(x + i);
    bf16x4_t o;
    o[0] = (bf16)v.x; o[1] = (bf16)v.y; o[2] = (bf16)v.z; o[3] = (bf16)v.w;
    *(bf16x4_t*)(xbf + i) = o;
  } else {
    int r = (b - 8192) * 256 + threadIdx.x;
    if (r >= 10240) return;
    bf16* dst; const float* src; int off;
    if (r < 4096)      { dst = Bqkv + (size_t)r * 64;        src = qB + (size_t)r * 16;          off = 0; }
    else if (r < 5120) { dst = Bqkv + (size_t)r * 64;        src = kB + (size_t)(r - 4096) * 16; off = 16; }
    else if (r < 6144) { dst = Bqkv + (size_t)r * 64;        src = vB + (size_t)(r - 5120) * 16; off = 32; }
    else               { dst = Bo + (size_t)(r - 6144) * 64; src = oB + (size_t)(r - 6144) * 16; off = 0; }
    bf16 row[64];
#pragma unroll
    for (int i = 0; i < 64; ++i) row[i] = (bf16)0.f;
#pragma unroll
    for (int i = 0; i < 16; ++i) row[off + i] = (bf16)src[i];
#pragma unroll
    for (int i = 0; i < 8; ++i)
      *(bf16x8_t*)(dst + i * 8) = *(bf16x8_t*)(row + i * 8);
  }
}

DEVI void dequant8(const int* idx, float sc, bf16* out) {
  int4 a = *(const int4*)idx;
  int4 b = *(const int4*)(idx + 4);
  bf16x8_t o;
  o[0] = (bf16)(NF4LUT[a.x] * sc);
  o[1] = (bf16)(NF4LUT[a.y] * sc);
  o[2] = (bf16)(NF4LUT[a.z] * sc);
  o[3] = (bf16)(NF4LUT[a.w] * sc);
  o[4] = (bf16)(NF4LUT[b.x] * sc);
  o[5] = (bf16)(NF4LUT[b.y] * sc);
  o[6] = (bf16)(NF4LUT[b.z] * sc);
  o[7] = (bf16)(NF4LUT[b.w] * sc);
  *(bf16x8_t*)out = o;
}

__global__ __launch_bounds__(256) void k_dequant(const int* __restrict__ idx,
                                                 const float* __restrict__ am,
                                                 bf16* __restrict__ out, int n) {
  int base = (blockIdx.x * 256 + threadIdx.x) * 8;
  if (base >= n) return;
  dequant8(idx + base, am[base >> 6], out + base);
}

// merged Q/K/V dequant into contiguous Wbuf (regions block-aligned)
__global__ __launch_bounds__(256) void k_dequant3(
    const int* __restrict__ i0, const float* __restrict__ a0,
    const int* __restrict__ i1, const float* __restrict__ a1,
    const int* __restrict__ i2, const float* __restrict__ a2,
    bf16* __restrict__ out) {
  size_t base = ((size_t)blockIdx.x * 256 + threadIdx.x) * 8;
  const int* idx; const float* am; size_t off;
  if (base < (size_t)4096 * 4096)      { idx = i0; am = a0; off = base; }
  else if (base < (size_t)5120 * 4096) { idx = i1; am = a1; off = base - (size_t)4096 * 4096; }
  else                                 { idx = i2; am = a2; off = base - (size_t)5120 * 4096; }
  dequant8(idx + off, am[off >> 6], out + base);
}

// merged RoPE for Q (width 4096, pre-scaled by 1/sqrt(128)*log2e for exp2
// softmax) and K (width 1024) sections of qkv[.][6144]
__global__ __launch_bounds__(256) void k_rope2(const bf16* __restrict__ qkv,
                                               bf16* __restrict__ qbf,
                                               bf16* __restrict__ kbf,
                                               const float* __restrict__ cs,
                                               const float* __restrict__ sn) {
  const float QSCL = 0.08838834764831843f * 1.4426950408889634f;
  int p = blockIdx.x * 256 + threadIdx.x;
  const bf16* in; bf16* out; int s, q; float scl;
  if (p < S * 2048) {
    s = p >> 11; q = p & 2047;
    int k = q & 63, col = ((q >> 6) << 7) + (k << 1);
    in = qkv + (size_t)s * NQKV + col;
    out = qbf + (size_t)s * D + col;
    scl = QSCL;
  } else {
    int p2 = p - S * 2048;
    s = p2 >> 9; q = p2 & 511;
    int k = q & 63, col = ((q >> 6) << 7) + (k << 1);
    in = qkv + (size_t)s * NQKV + 4096 + col;
    out = kbf + (size_t)s * KVW + col;
    scl = 1.0f;
  }
  int k = q & 63;
  bf16x2_t v = *(const bf16x2_t*)in;
  float xr = (float)v[0], xi = (float)v[1];
  float c = cs[s * 64 + k], si = sn[s * 64 + k];
  bf16x2_t o;
  o[0] = (bf16)((xr * c - xi * si) * scl);
  o[1] = (bf16)((xr * si + xi * c) * scl);
  *(bf16x2_t*)out = o;
}

// transpose V section of qkv (cols 5120..6143) into vT[1024][2048]
__global__ __launch_bounds__(256) void k_transpose_v(const bf16* __restrict__ qkv,
                                                     bf16* __restrict__ vT) {
  __shared__ bf16 tl[64][72];
  const int t = threadIdx.x;
  const int s0 = blockIdx.x * 64, d0 = blockIdx.y * 64;
  int r = t >> 3, c = (t & 7) * 8;
  *(bf16x8_t*)&tl[r][c] = *(const bf16x8_t*)&qkv[(size_t)(s0 + r) * NQKV + 5120 + d0 + c];
  *(bf16x8_t*)&tl[r + 32][c] = *(const bf16x8_t*)&qkv[(size_t)(s0 + r + 32) * NQKV + 5120 + d0 + c];
  __syncthreads();
  int dr = t >> 3, sc = (t & 7) * 8;
  bf16x8_t o0, o1;
#pragma unroll
  for (int i = 0; i < 8; ++i) { o0[i] = tl[sc + i][dr]; o1[i] = tl[sc + i][dr + 32]; }
  *(bf16x8_t*)&vT[(size_t)(d0 + dr) * S + s0 + sc] = o0;
  *(bf16x8_t*)&vT[(size_t)(d0 + dr + 32) * S + s0 + sc] = o1;
}

// ---------------- skinny LoRA-left GEMM, split-K=16: part[ks][s][r]
__global__ __launch_bounds__(256) void k_lora_skinny(
    const bf16* __restrict__ X, const float* __restrict__ A0,
    const float* __restrict__ A1, const float* __restrict__ A2,
    float* __restrict__ part) {
  __shared__ __align__(16) bf16 Xs[128 * 32];
  __shared__ __align__(16) bf16 Bs[64 * 32];
  const int tid = threadIdx.x;
  const int rowBase = blockIdx.x * 128;
  const int k0base = blockIdx.y * 256;
  const int l = tid & 63, wv = tid >> 6;
  const int wr = (wv >> 1) * 64, wc = (wv & 1) * 32;
  const int lr = l & 15, lk = (l >> 4) * 8, lg = (l >> 4) * 4;

  f32x4_t acc[4][2];
#pragma unroll
  for (int m = 0; m < 4; ++m)
#pragma unroll
    for (int n = 0; n < 2; ++n) acc[m][n] = f32x4_t{0.f, 0.f, 0.f, 0.f};

  for (int k0 = k0base; k0 < k0base + 256; k0 += 32) {
    __syncthreads();
    gld_lds16(X + (size_t)(rowBase + (tid >> 2)) * D + k0 + (tid & 3) * 8, Xs + tid * 8);
    gld_lds16(X + (size_t)(rowBase + 64 + (tid >> 2)) * D + k0 + (tid & 3) * 8,
              Xs + 2048 + tid * 8);
#pragma unroll
    for (int j = 0; j < 2; ++j) {
      int r = j * 32 + (tid >> 3);
      int c = (tid & 7) * 4;
      const float* Ap = nullptr; int rr = r;
      if (r < 16) Ap = A0;
      else if (r < 32) { Ap = A1; rr = r - 16; }
      else if (r < 48) { Ap = A2; rr = r - 32; }
      bf16x4_t b = {bf16(0.f), bf16(0.f), bf16(0.f), bf16(0.f)};
      if (Ap) {
        float4 v = *(const float4*)&Ap[(size_t)rr * D + k0 + c];
        b[0] = (bf16)v.x; b[1] = (bf16)v.y; b[2] = (bf16)v.z; b[3] = (bf16)v.w;
      }
      *(bf16x4_t*)&Bs[r * 32 + c] = b;
    }
    __syncthreads();
    bf16x8_t af[4], bfr[2];
#pragma unroll
    for (int m = 0; m < 4; ++m)
      af[m] = *(const bf16x8_t*)&Xs[(wr + m * 16 + lr) * 32 + lk];
#pragma unroll
    for (int n = 0; n < 2; ++n)
      bfr[n] = *(const bf16x8_t*)&Bs[(wc + n * 16 + lr) * 32 + lk];
#pragma unroll
    for (int m = 0; m < 4; ++m)
#pragma unroll
      for (int n = 0; n < 2; ++n)
        acc[m][n] = __builtin_amdgcn_mfma_f32_16x16x32_bf16(af[m], bfr[n],
                                                            acc[m][n], 0, 0, 0);
  }
#pragma unroll
  for (int m = 0; m < 4; ++m)
#pragma unroll
    for (int n = 0; n < 2; ++n)
#pragma unroll
      for (int g = 0; g < 4; ++g)
        part[(size_t)blockIdx.y * (2048 * 64) +
             (size_t)(rowBase + wr + m * 16 + lg + g) * 64 + wc + n * 16 + lr] =
            acc[m][n][g];
}

__global__ __launch_bounds__(256) void k_lora_reduce(const float* __restrict__ part,
                                                     bf16* __restrict__ out) {
  int i = blockIdx.x * 256 + threadIdx.x;
  float s = 0.f;
#pragma unroll
  for (int j = 0; j < 16; ++j) s += part[j * 131072 + i];
  out[i] = (bf16)(2.0f * s);
}

// ---------------- main GEMM: out[s][n] = sum_d A[s][d]*W[n][d] + rank-64 tail
// 128x128 tile, BK=64 (XOR-swizzled LDS), 4 waves, 16x16x32 bf16 MFMA.
// Column-major block order within XCD-contiguous chunks for W-panel L2 reuse.
// (r7/r9/r13-proven: ~1030 TF, 0 bank conflicts. r8 dbuf and r10 fused-epilogue
//  variants both regressed via occupancy/L2-reuse loss — keep this lean.)

template <int OUT_BF16>
__global__ __launch_bounds__(256) void k_gemm_lora(
    const bf16* __restrict__ Ag, const bf16* __restrict__ Wg,
    const bf16* __restrict__ xA64, const bf16* __restrict__ Bl64,
    void* __restrict__ outp, int N, int K) {
  __shared__ __align__(16) bf16 As[128 * 64];
  __shared__ __align__(16) bf16 Bs[128 * 64];
  const int tid = threadIdx.x;
  const int gy = gridDim.y;                 // 16 row-blocks
  const int nwg = gridDim.x * gy;
  const int flat = blockIdx.y * gridDim.x + blockIdx.x;
  const int cpx = nwg >> 3;
  const int bid = (flat & 7) * cpx + (flat >> 3);   // XCD-contiguous chunks
  const int colBase = (bid / gy) * 128;             // column-major within chunk
  const int rowBase = (bid % gy) * 128;
  const int l = tid & 63, wv = tid >> 6;
  const int wr = (wv >> 1) * 64, wc = (wv & 1) * 64;
  const int lr = l & 15, lk = (l >> 4) * 8;

  f32x4_t acc[4][4];
#pragma unroll
  for (int m = 0; m < 4; ++m)
#pragma unroll
    for (int n = 0; n < 4; ++n) acc[m][n] = f32x4_t{0.f, 0.f, 0.f, 0.f};

  // stage a [128][64] tile (rows at stride ld from src), source-swizzled
  auto stage = [&](const bf16* src, size_t ld, bf16* dst) {
#pragma unroll
    for (int j = 0; j < 4; ++j) {
      int r = j * 32 + (tid >> 3);
      int c = ((tid & 7) * 8) ^ swz64(r);
      gld_lds16(src + (size_t)r * ld + c, dst + j * 2048 + tid * 8);
    }
  };

  auto compute = [&]() {
#pragma unroll
    for (int kk = 0; kk < 2; ++kk) {
      bf16x8_t af[4], bfr[4];
#pragma unroll
      for (int m = 0; m < 4; ++m) {
        int r = wr + m * 16 + lr;
        af[m] = *(const bf16x8_t*)&As[r * 64 + ((kk * 32 + lk) ^ swz64(r))];
      }
#pragma unroll
      for (int n = 0; n < 4; ++n) {
        int r = wc + n * 16 + lr;
        bfr[n] = *(const bf16x8_t*)&Bs[r * 64 + ((kk * 32 + lk) ^ swz64(r))];
      }
      __builtin_amdgcn_s_setprio(1);
#pragma unroll
      for (int m = 0; m < 4; ++m)
#pragma unroll
        for (int n = 0; n < 4; ++n)
          acc[m][n] = __builtin_amdgcn_mfma_f32_16x16x32_bf16(af[m], bfr[n],
                                                              acc[m][n], 0, 0, 0);
      __builtin_amdgcn_s_setprio(0);
    }
  };

  for (int k0 = 0; k0 < K; k0 += 64) {
    __syncthreads();
    stage(Ag + (size_t)rowBase * K + k0, K, As);
    stage(Wg + (size_t)colBase * K + k0, K, Bs);
    __syncthreads();
    compute();
  }

  // rank-64 LoRA tail: one BK=64 step from xA64 [M][64] and Bl64 [N][64]
  __syncthreads();
  stage(xA64 + (size_t)rowBase * 64, 64, As);
  stage(Bl64 + (size_t)colBase * 64, 64, Bs);
  __syncthreads();
  compute();

#pragma unroll
  for (int m = 0; m < 4; ++m)
#pragma unroll
    for (int n = 0; n < 4; ++n)
#pragma unroll
      for (int g = 0; g < 4; ++g) {
        int grow = rowBase + wr + m * 16 + ((l >> 4) << 2) + g;
        int gcol = colBase + wc + n * 16 + (l & 15);
        if (OUT_BF16)
          ((bf16*)outp)[(size_t)grow * N + gcol] = (bf16)acc[m][n][g];
        else
          ((float*)outp)[(size_t)grow * N + gcol] = acc[m][n][g];
      }
}

// ---------------- flash attention (causal, GQA 4:1) ----------------
// 512 thr / 8 waves; QBLK=128 (16 rows/wave), KVBLK=64, double-buffered.
// r14-proven (+11.5us vs 4-wave): waves/SIMD 2->4 latency hiding; per-wave
// state fits the 128-VGPR cap (r15 split-KV doubled state -> spill, -140us).
// Q pre-scaled by 1/sqrt(128)*log2e -> exp2 softmax; defer-max THR=8;
// per-lane denominator reduced once at the end.

__global__ __launch_bounds__(512, 4) void k_flash(const bf16* __restrict__ Qg,
                                                  const bf16* __restrict__ Kg,
                                                  const bf16* __restrict__ vTg,
                                                  bf16* __restrict__ Og) {
  __shared__ __align__(16) bf16 Kt[2][64 * 128];   // 32 KB
  __shared__ __align__(16) bf16 Vt[2][128 * 64];   // 32 KB
  __shared__ __align__(16) bf16 Pl[8][16 * 64];    // 16 KB
  const int tid = threadIdx.x, l = tid & 63, wv = tid >> 6;   // wv 0..7
  const int h = blockIdx.y, hkv = h >> 2;
  const int qb = (h < 16) ? (15 - (int)blockIdx.x) : (int)blockIdx.x;
  const int lr = l & 15, lk = (l >> 4) * 8, lg = (l >> 4) * 4;
  const int swz = (lr & 7) << 3;

  const int R0 = qb * 128 + wv * 16;
  bf16x8_t qf[4];
#pragma unroll
  for (int s4 = 0; s4 < 4; ++s4)
    qf[s4] = *(const bf16x8_t*)&Qg[(size_t)(R0 + lr) * D + h * HD + s4 * 32 + lk];

  f32x4_t O[8];
#pragma unroll
  for (int of = 0; of < 8; ++of) O[of] = f32x4_t{0.f, 0.f, 0.f, 0.f};
  float mrun[4], lpart[4];
#pragma unroll
  for (int g = 0; g < 4; ++g) { mrun[g] = -1e30f; lpart[g] = 0.f; }

  auto stage = [&](int b, int t) {
    const int kv0 = t * 64;
#pragma unroll
    for (int j = 0; j < 2; ++j) {
      int kr = j * 32 + (tid >> 4);                    // 0..63
      int kc = ((tid & 15) * 8) ^ ((kr & 7) << 3);
      gld_lds16(Kg + (size_t)(kv0 + kr) * KVW + hkv * HD + kc,
                &Kt[b][j * 4096 + tid * 8]);
    }
#pragma unroll
    for (int j = 0; j < 2; ++j) {
      int vr = j * 64 + (tid >> 3);                    // 0..127
      int vc = ((tid & 7) * 8) ^ ((vr & 7) << 3);
      gld_lds16(vTg + (size_t)(hkv * HD + vr) * S + kv0 + vc,
                &Vt[b][j * 4096 + tid * 8]);
    }
  };

  const int nt = 2 * qb + 2;
  stage(0, 0);

  for (int t = 0; t < nt; ++t) {
    __syncthreads();
    if (t + 1 < nt) stage((t + 1) & 1, t + 1);
    const bf16* Kb = Kt[t & 1];
    const bf16* Vb = Vt[t & 1];
    const int kv0 = t * 64;

    // S = Q K^T (pre-scaled logits in log2 units)
    f32x4_t sc[4];
#pragma unroll
    for (int cb = 0; cb < 4; ++cb) sc[cb] = f32x4_t{0.f, 0.f, 0.f, 0.f};
#pragma unroll
    for (int cb = 0; cb < 4; ++cb) {
      __builtin_amdgcn_s_setprio(1);
#pragma unroll
      for (int s4 = 0; s4 < 4; ++s4) {
        bf16x8_t kf = *(const bf16x8_t*)&Kb[(cb * 16 + lr) * 128 +
                                            ((s4 * 32 + lk) ^ swz)];
        sc[cb] = __builtin_amdgcn_mfma_f32_16x16x32_bf16(qf[s4], kf, sc[cb],
                                                         0, 0, 0);
      }
      __builtin_amdgcn_s_setprio(0);
    }

    const bool diag = (t >= 2 * qb);
    if (diag) {
#pragma unroll
      for (int cb = 0; cb < 4; ++cb)
#pragma unroll
        for (int g = 0; g < 4; ++g)
          if (kv0 + cb * 16 + lr > R0 + lg + g) sc[cb][g] = -1e30f;
    }

    // local per-lane tile max; defer-max test (wave-uniform branch)
    float lmax[4];
    bool ok = true;
#pragma unroll
    for (int g = 0; g < 4; ++g) {
      lmax[g] = fmaxf(fmaxf(sc[0][g], sc[1][g]), fmaxf(sc[2][g], sc[3][g]));
      ok &= (lmax[g] <= mrun[g] + 8.0f);
    }
    if (!__all(ok)) {
#pragma unroll
      for (int g = 0; g < 4; ++g) {
        float mx = lmax[g];
        mx = fmaxf(mx, __shfl_xor(mx, 1));
        mx = fmaxf(mx, __shfl_xor(mx, 2));
        mx = fmaxf(mx, __shfl_xor(mx, 4));
        mx = fmaxf(mx, __shfl_xor(mx, 8));
        float mnew = fmaxf(mrun[g], mx);
        float corr = exp2f(mrun[g] - mnew);
        mrun[g] = mnew;
        lpart[g] *= corr;
#pragma unroll
        for (int of = 0; of < 8; ++of) O[of][g] *= corr;
      }
    }

    // P = exp2(S - mrun); accumulate per-lane denominator; P -> swizzled LDS
#pragma unroll
    for (int cb = 0; cb < 4; ++cb)
#pragma unroll
      for (int g = 0; g < 4; ++g) {
        float p = exp2f(sc[cb][g] - mrun[g]);
        sc[cb][g] = p;
        lpart[g] += p;
      }
#pragma unroll
    for (int cb = 0; cb < 4; ++cb)
#pragma unroll
      for (int g = 0; g < 4; ++g) {
        int row = lg + g;
        Pl[wv][row * 64 + ((cb * 16 + lr) ^ ((row & 7) << 3))] = (bf16)sc[cb][g];
      }

    // O += P V
    bf16x8_t pf[2];
#pragma unroll
    for (int s = 0; s < 2; ++s)
      pf[s] = *(const bf16x8_t*)&Pl[wv][lr * 64 + ((s * 32 + lk) ^ ((lr & 7) << 3))];
#pragma unroll
    for (int of = 0; of < 8; ++of) {
      __builtin_amdgcn_s_setprio(1);
#pragma unroll
      for (int s = 0; s < 2; ++s) {
        bf16x8_t vf = *(const bf16x8_t*)&Vb[(of * 16 + lr) * 64 +
                                            ((s * 32 + lk) ^ swz)];
        O[of] = __builtin_amdgcn_mfma_f32_16x16x32_bf16(pf[s], vf, O[of], 0, 0, 0);
      }
      __builtin_amdgcn_s_setprio(0);
    }
  }

  // final: reduce per-lane denominator across the 16-lane group, write O
  float inv[4];
#pragma unroll
  for (int g = 0; g < 4; ++g) {
    float r = lpart[g];
    r += __shfl_xor(r, 1); r += __shfl_xor(r, 2);
    r += __shfl_xor(r, 4); r += __shfl_xor(r, 8);
    inv[g] = 1.0f / r;
  }
#pragma unroll
  for (int of = 0; of < 8; ++of)
#pragma unroll
    for (int g = 0; g < 4; ++g)
      Og[(size_t)(R0 + lg + g) * D + h * HD + of * 16 + lr] =
          (bf16)(O[of][g] * inv[g]);
}

// ---------------- launch ----------------

extern "C" void kernel_launch(void* const* d_in, const int* in_sizes, int n_in,
                              void* d_out, int out_size, void* d_ws, size_t ws_size,
                              hipStream_t stream) {
  const float* x    = (const float*)d_in[0];
  const float* cosb = (const float*)d_in[1];
  const float* sinb = (const float*)d_in[2];
  const int*   wq_idx = (const int*)d_in[4];
  const float* wq_am  = (const float*)d_in[5];
  const float* wq_A   = (const float*)d_in[6];
  const float* wq_B   = (const float*)d_in[7];
  const int*   wk_idx = (const int*)d_in[8];
  const float* wk_am  = (const float*)d_in[9];
  const float* wk_A   = (const float*)d_in[10];
  const float* wk_B   = (const float*)d_in[11];
  const int*   wv_idx = (const int*)d_in[12];
  const float* wv_am  = (const float*)d_in[13];
  const float* wv_A   = (const float*)d_in[14];
  const float* wv_B   = (const float*)d_in[15];
  const int*   wo_idx = (const int*)d_in[16];
  const float* wo_am  = (const float*)d_in[17];
  const float* wo_A   = (const float*)d_in[18];
  const float* wo_B   = (const float*)d_in[19];

  char* w = (char*)d_ws;
  auto alloc = [&](size_t bytes) {
    char* p = w;
    w += (bytes + 255) & ~(size_t)255;
    return p;
  };
  bf16*  xbf   = (bf16*)alloc((size_t)S * D * 2);            // 16 MB
  bf16*  Wbuf  = (bf16*)alloc((size_t)NQKV * 4096 * 2);      // 50 MB
  bf16*  qkv   = (bf16*)alloc((size_t)S * NQKV * 2);         // 25 MB
  bf16*  qbf   = (bf16*)alloc((size_t)S * D * 2);            // 16 MB
  bf16*  kbf   = (bf16*)alloc((size_t)S * KVW * 2);          // 4 MB
  bf16*  vT    = (bf16*)alloc((size_t)KVW * S * 2);          // 4 MB
  bf16*  abf   = (bf16*)alloc((size_t)S * D * 2);            // 16 MB
  float* part  = (float*)alloc((size_t)16 * S * 64 * 4);     // 8 MB
  bf16*  xA64  = (bf16*)alloc((size_t)S * 64 * 2);
  bf16*  xA64o = (bf16*)alloc((size_t)S * 64 * 2);
  bf16*  Bqkv  = (bf16*)alloc((size_t)NQKV * 64 * 2);
  bf16*  Bo64  = (bf16*)alloc((size_t)4096 * 64 * 2);

  // prep (x convert + lora-B pack, one launch)
  k_prep<<<8232, 256, 0, stream>>>(x, xbf, wq_B, wk_B, wv_B, wo_B, Bqkv, Bo64);
  k_lora_skinny<<<dim3(16, 16), 256, 0, stream>>>(xbf, wq_A, wk_A, wv_A, part);
  k_lora_reduce<<<512, 256, 0, stream>>>(part, xA64);

  // merged QKV dequant + projection (N = 6144)
  k_dequant3<<<12288, 256, 0, stream>>>(wq_idx, wq_am, wk_idx, wk_am,
                                        wv_idx, wv_am, Wbuf);
  k_gemm_lora<1><<<dim3(48, 16), 256, 0, stream>>>(xbf, Wbuf, xA64, Bqkv,
                                                   qkv, NQKV, D);
  k_rope2<<<20480, 256, 0, stream>>>(qkv, qbf, kbf, cosb, sinb);
  k_transpose_v<<<dim3(32, 16), 256, 0, stream>>>(qkv, vT);

  // attention (512-thread blocks, 8 waves)
  k_flash<<<dim3(16, 32), 512, 0, stream>>>(qbf, kbf, vT, abf);

  // output projection
  k_lora_skinny<<<dim3(16, 16), 256, 0, stream>>>(abf, wo_A, nullptr, nullptr, part);
  k_lora_reduce<<<512, 256, 0, stream>>>(part, xA64o);
  k_dequant<<<8192, 256, 0, stream>>>(wo_idx, wo_am, Wbuf, 4096 * 4096);
  k_gemm_lora<0><<<dim3(32, 16), 256, 0, stream>>>(abf, Wbuf, xA64o, Bo64,
                                                   (float*)d_out, D, D);
}